// Round 2
// baseline (87.162 us; speedup 1.0000x reference)
//
#include <hip/hip_runtime.h>

// FuzzyLayer: out[b] = exp(-sum_{i,o} sqrt((x[b] - fd[i,o]) / sigma[i,o]^2)),
// NaN -> x[b].  B=262144 samples, 1024 params.
// Transcendental-bound: 268M v_sqrt_f32. One thread per sample; params staged
// in LDS as float2 (inv_sigma2, -fd*inv_sigma2) so inner loop is
// ds_read_b64(broadcast) + v_fma + v_sqrt + v_add. 4 accumulators for ILP.
// NOTE: __sqrtf does not exist in HIP (CUDA-ism, collides with glibc math.h);
// use __builtin_amdgcn_sqrtf -> raw v_sqrt_f32.

constexpr int NPAR = 1024;   // 32*32
constexpr int BLOCK = 256;

__global__ __launch_bounds__(BLOCK) void fuzzy_kernel(
    const float* __restrict__ x,
    const float* __restrict__ fd,
    const float* __restrict__ sigma,
    float* __restrict__ out,
    int B)
{
    __shared__ float2 p[NPAR];
    const int tid = threadIdx.x;

    // Stage params: a = 1/sigma^2, c = -fd * a  =>  diff = fma(x, a, c)
    // Exact for the test input (sigma == 1 -> a == 1, c == -fd).
    for (int k = tid; k < NPAR; k += BLOCK) {
        float sg  = sigma[k];
        float inv = 1.0f / (sg * sg);
        p[k] = make_float2(inv, -fd[k] * inv);
    }
    __syncthreads();

    const int i = blockIdx.x * BLOCK + tid;
    const float xv = (i < B) ? x[i] : 0.0f;

    float s0 = 0.0f, s1 = 0.0f, s2 = 0.0f, s3 = 0.0f;
#pragma unroll 2
    for (int k = 0; k < NPAR; k += 4) {
        float2 p0 = p[k + 0];
        float2 p1 = p[k + 1];
        float2 p2 = p[k + 2];
        float2 p3 = p[k + 3];
        s0 += __builtin_amdgcn_sqrtf(fmaf(xv, p0.x, p0.y));
        s1 += __builtin_amdgcn_sqrtf(fmaf(xv, p1.x, p1.y));
        s2 += __builtin_amdgcn_sqrtf(fmaf(xv, p2.x, p2.y));
        s3 += __builtin_amdgcn_sqrtf(fmaf(xv, p3.x, p3.y));
    }
    float s = (s0 + s1) + (s2 + s3);
    float o = __expf(-s);          // underflows to 0 for s > ~104, matching jnp
    if (i < B) {
        out[i] = (o != o) ? xv : o;  // NaN (any diff < 0) -> raw input sample
    }
}

extern "C" void kernel_launch(void* const* d_in, const int* in_sizes, int n_in,
                              void* d_out, int out_size, void* d_ws, size_t ws_size,
                              hipStream_t stream) {
    const float* x     = (const float*)d_in[0];
    const float* fd    = (const float*)d_in[1];
    const float* sigma = (const float*)d_in[2];
    float* out = (float*)d_out;
    const int B = in_sizes[0];

    const int grid = (B + BLOCK - 1) / BLOCK;
    fuzzy_kernel<<<grid, BLOCK, 0, stream>>>(x, fd, sigma, out, B);
}

// Round 3
// 60.729 us; speedup vs baseline: 1.4353x; 1.4353x over previous
//
#include <hip/hip_runtime.h>

// FuzzyLayer: out[b] = exp(-sum_{i,o} sqrt((x[b] - fd[i,o]) / sigma[i,o]^2)),
// NaN -> x[b].  B=262144 samples, 1024 params.
//
// Key algebra: with a_k = 1/sigma_k^2, c_k = -fd_k * a_k, each term is
// sqrt(a_k*x + c_k). If all a_k,c_k are finite and >= 0, s(x) is monotone
// increasing in x, so for x >= 0:  s(x) >= s(0) = sum sqrt(c_k).
// If s(0) >= 104, expf(-s) underflows to exactly 0 (f32 cutoff ~103.98) for
// every x >= 0 -> out = 0 with NO per-sample sqrt work. A one-block
// precompute kernel validates this from the actual device data each call;
// lanes that fail the guard (x<0, NaN, weird params) take the full loop,
// preserving exact semantics incl. the NaN -> x fallback.
// Measured r2: full loop ~45us (v_sqrt_f32 pipe-bound); fast path ~2us.

constexpr int NPAR  = 1024;   // 32*32
constexpr int BLOCK = 256;
constexpr float S0_CUTOFF = 104.0f;
constexpr float FIN_MAX   = 3.0e38f;

__global__ __launch_bounds__(BLOCK) void precompute_kernel(
    const float* __restrict__ fd,
    const float* __restrict__ sigma,
    int* __restrict__ flag_ws)
{
    __shared__ float ssum[BLOCK];
    __shared__ int   sok[BLOCK];
    const int tid = threadIdx.x;

    float local = 0.0f;
    int ok = 1;
    for (int k = tid; k < NPAR; k += BLOCK) {
        float sg  = sigma[k];
        float inv = 1.0f / (sg * sg);
        float c   = -fd[k] * inv;
        // require a_k, c_k finite and >= 0 (NaN fails every comparison)
        if (!(inv > 0.0f) || !(inv <= FIN_MAX) ||
            !(c >= 0.0f)  || !(c   <= FIN_MAX)) ok = 0;
        local += __builtin_amdgcn_sqrtf(c);
    }
    ssum[tid] = local;
    sok[tid]  = ok;
    __syncthreads();
    for (int s = BLOCK / 2; s > 0; s >>= 1) {
        if (tid < s) { ssum[tid] += ssum[tid + s]; sok[tid] &= sok[tid + s]; }
        __syncthreads();
    }
    if (tid == 0) flag_ws[0] = (sok[0] && (ssum[0] >= S0_CUTOFF)) ? 1 : 0;
}

__global__ __launch_bounds__(BLOCK) void fuzzy_kernel(
    const float* __restrict__ x,
    const float* __restrict__ fd,
    const float* __restrict__ sigma,
    float* __restrict__ out,
    const int* __restrict__ flag_ws,
    int B)
{
    __shared__ float2 p[NPAR];
    __shared__ int block_slow;

    const int tid = threadIdx.x;
    const int i   = blockIdx.x * BLOCK + tid;
    const float xv = (i < B) ? x[i] : 0.0f;

    const int flag = flag_ws[0];           // uniform scalar load
    const int fast = flag && (xv >= 0.0f); // NaN xv -> slow path

    if (tid == 0) block_slow = 0;
    __syncthreads();
    if (!fast) block_slow = 1;             // race-benign LDS store
    __syncthreads();

    if (!block_slow) {                     // block-uniform fast path
        if (i < B) out[i] = 0.0f;          // guaranteed exp underflow
        return;
    }

    // --- full path (generic fallback; exact semantics) ---
    for (int k = tid; k < NPAR; k += BLOCK) {
        float sg  = sigma[k];
        float inv = 1.0f / (sg * sg);
        p[k] = make_float2(inv, -fd[k] * inv);
    }
    __syncthreads();

    float s0 = 0.0f, s1 = 0.0f, s2 = 0.0f, s3 = 0.0f;
#pragma unroll 2
    for (int k = 0; k < NPAR; k += 4) {
        float2 p0 = p[k + 0];
        float2 p1 = p[k + 1];
        float2 p2 = p[k + 2];
        float2 p3 = p[k + 3];
        s0 += __builtin_amdgcn_sqrtf(fmaf(xv, p0.x, p0.y));
        s1 += __builtin_amdgcn_sqrtf(fmaf(xv, p1.x, p1.y));
        s2 += __builtin_amdgcn_sqrtf(fmaf(xv, p2.x, p2.y));
        s3 += __builtin_amdgcn_sqrtf(fmaf(xv, p3.x, p3.y));
    }
    float s = (s0 + s1) + (s2 + s3);
    float o = __expf(-s);
    if (i < B) {
        out[i] = (o != o) ? xv : o;        // NaN -> raw input sample
    }
}

extern "C" void kernel_launch(void* const* d_in, const int* in_sizes, int n_in,
                              void* d_out, int out_size, void* d_ws, size_t ws_size,
                              hipStream_t stream) {
    const float* x     = (const float*)d_in[0];
    const float* fd    = (const float*)d_in[1];
    const float* sigma = (const float*)d_in[2];
    float* out   = (float*)d_out;
    int*   flag  = (int*)d_ws;             // recomputed every call (ws is re-poisoned)
    const int B  = in_sizes[0];

    precompute_kernel<<<1, BLOCK, 0, stream>>>(fd, sigma, flag);
    const int grid = (B + BLOCK - 1) / BLOCK;
    fuzzy_kernel<<<grid, BLOCK, 0, stream>>>(x, fd, sigma, out, flag, B);
}

// Round 4
// 59.099 us; speedup vs baseline: 1.4749x; 1.0276x over previous
//
#include <hip/hip_runtime.h>

// FuzzyLayer: out[b] = exp(-sum_{i,o} sqrt((x[b] - fd[i,o]) / sigma[i,o]^2)),
// NaN -> x[b].  B=262144 samples, 1024 params.
//
// Algebra: with a_k = 1/sigma_k^2, c_k = -fd_k*a_k, each term is
// sqrt(a_k*x + c_k). If all a_k,c_k finite & >= 0, s(x) is monotone in x, so
// for x >= 0: s(x) >= s(0) = sum sqrt(c_k). If s(0) >= 104, expf(-s)
// underflows to exactly 0 for every x >= 0 -> out = 0, no per-sample sqrt.
// r3 post-mortem: separate 1-block precompute kernel + scalar I/O cost ~19us
// of launch/serialization overhead on top of the harness's fixed 40us
// ws-poison fill. Fused: every block computes the guard itself while staging
// p[] (4 sqrt + tree-reduce per block, parallel, ~free), float4 I/O.

constexpr int NPAR  = 1024;   // 32*32
constexpr int BLOCK = 256;
constexpr float S0_CUTOFF = 104.0f;
constexpr float FIN_MAX   = 3.0e38f;

__global__ __launch_bounds__(BLOCK) void fuzzy_fused(
    const float* __restrict__ x,
    const float* __restrict__ fd,
    const float* __restrict__ sigma,
    float* __restrict__ out,
    int B)
{
    __shared__ float2 p[NPAR];
    __shared__ float  ssum[BLOCK];
    __shared__ int    sok[BLOCK];
    __shared__ int    block_slow;

    const int tid = threadIdx.x;

    // Stage params into LDS AND accumulate the guard in one pass.
    float local = 0.0f;
    int ok = 1;
    for (int k = tid; k < NPAR; k += BLOCK) {
        float sg  = sigma[k];
        float inv = 1.0f / (sg * sg);
        float c   = -fd[k] * inv;
        p[k] = make_float2(inv, c);
        // require a_k, c_k finite and >= 0 (NaN fails every comparison)
        if (!(inv > 0.0f) || !(inv <= FIN_MAX) ||
            !(c >= 0.0f)  || !(c   <= FIN_MAX)) ok = 0;
        local += __builtin_amdgcn_sqrtf(c);
    }
    ssum[tid] = local;
    sok[tid]  = ok;
    if (tid == 0) block_slow = 0;
    __syncthreads();
    for (int s = BLOCK / 2; s > 0; s >>= 1) {
        if (tid < s) { ssum[tid] += ssum[tid + s]; sok[tid] &= sok[tid + s]; }
        __syncthreads();
    }
    const bool guard = sok[0] && (ssum[0] >= S0_CUTOFF);

    // 4 samples per thread, float4 I/O.
    const int base = (blockIdx.x * BLOCK + tid) * 4;
    float4 xv = make_float4(0.0f, 0.0f, 0.0f, 0.0f);
    const bool full4 = (base + 3 < B);
    if (full4) {
        xv = *(const float4*)(x + base);
    } else if (base < B) {
        float* xs = (float*)&xv;
        for (int j = 0; j < 4 && base + j < B; ++j) xs[j] = x[base + j];
    }

    const bool lane_fast = guard &&
        (xv.x >= 0.0f) && (xv.y >= 0.0f) &&
        (xv.z >= 0.0f) && (xv.w >= 0.0f);   // NaN -> false -> slow
    if (!lane_fast) block_slow = 1;          // race-benign vote
    __syncthreads();

    if (!block_slow) {                       // block-uniform fast path
        if (full4) {
            *(float4*)(out + base) = make_float4(0.0f, 0.0f, 0.0f, 0.0f);
        } else {
            for (int j = 0; j < 4 && base + j < B; ++j) out[base + j] = 0.0f;
        }
        return;
    }

    // --- full fallback (exact semantics, incl. NaN -> x) ---
    const float* xs = (const float*)&xv;
    float r[4];
    for (int j = 0; j < 4; ++j) {
        const float v = xs[j];
        float s0 = 0.0f, s1 = 0.0f, s2 = 0.0f, s3 = 0.0f;
#pragma unroll 2
        for (int k = 0; k < NPAR; k += 4) {
            float2 p0 = p[k + 0];
            float2 p1 = p[k + 1];
            float2 p2 = p[k + 2];
            float2 p3 = p[k + 3];
            s0 += __builtin_amdgcn_sqrtf(fmaf(v, p0.x, p0.y));
            s1 += __builtin_amdgcn_sqrtf(fmaf(v, p1.x, p1.y));
            s2 += __builtin_amdgcn_sqrtf(fmaf(v, p2.x, p2.y));
            s3 += __builtin_amdgcn_sqrtf(fmaf(v, p3.x, p3.y));
        }
        float s = (s0 + s1) + (s2 + s3);
        float o = __expf(-s);
        r[j] = (o != o) ? v : o;
    }
    if (full4) {
        *(float4*)(out + base) = make_float4(r[0], r[1], r[2], r[3]);
    } else {
        for (int j = 0; j < 4 && base + j < B; ++j) out[base + j] = r[j];
    }
}

extern "C" void kernel_launch(void* const* d_in, const int* in_sizes, int n_in,
                              void* d_out, int out_size, void* d_ws, size_t ws_size,
                              hipStream_t stream) {
    const float* x     = (const float*)d_in[0];
    const float* fd    = (const float*)d_in[1];
    const float* sigma = (const float*)d_in[2];
    float* out  = (float*)d_out;
    const int B = in_sizes[0];

    const int grid = (B + BLOCK * 4 - 1) / (BLOCK * 4);
    fuzzy_fused<<<grid, BLOCK, 0, stream>>>(x, fd, sigma, out, B);
}

// Round 5
// 58.151 us; speedup vs baseline: 1.4989x; 1.0163x over previous
//
#include <hip/hip_runtime.h>

// FuzzyLayer: out[b] = exp(-sum_{i,o} sqrt((x[b] - fd[i,o]) / sigma[i,o]^2)),
// NaN -> x[b].  B=262144 samples, 1024 params.
//
// Fast-path algebra: if every param satisfies fd<=0 (finite) and sigma^2 in
// [1e-30,1e30], then each term sqrt((x-fd)/sigma^2) is real for x>=0 and
// s(x) >= s(0) = sum sqrt(-fd/sigma^2). If s(0) >= 128 (actual ~266 here,
// f32 exp underflow cutoff ~104), out is exactly 0 for every x>=0 -> no
// per-sample transcendental work at all.
//
// r4 post-mortem: residual ~15us over the harness's fixed 40.5us ws-poison
// is mostly graph-node overhead + this kernel's critical path (exact
// divisions, 8KB LDS staging, 10 barriers, at 1 block/CU). This version:
// one float4 param load per thread, approx rcp/sqrt guard, wave shfl_xor
// reduce, ONE barrier, per-lane slow fallback straight from global (exact
// reference arithmetic, exec-masked off when unused). No staging, no vote.

constexpr int NPAR  = 1024;   // 32*32 == BLOCK*4
constexpr int BLOCK = 256;
constexpr int VPT   = 4;      // samples per thread
constexpr float S0_CUTOFF = 128.0f;   // >104 underflow cutoff, margin for rcp approx

__global__ __launch_bounds__(BLOCK) void fuzzy_fused(
    const float* __restrict__ x,
    const float* __restrict__ fd,
    const float* __restrict__ sigma,
    float* __restrict__ out,
    int B)
{
    __shared__ float wsum[BLOCK / 64];
    __shared__ int   wok[BLOCK / 64];
    const int tid  = threadIdx.x;
    const int wave = tid >> 6;

    // ---- guard: each thread validates 4 params (NPAR == BLOCK*4) ----
    float local = 0.0f;
    int ok = 1;
    {
        const int k = tid * 4;           // NPAR==1024: always in range
        const float4 f = *(const float4*)(fd + k);
        const float4 g = *(const float4*)(sigma + k);
        const float* fe = (const float*)&f;
        const float* ge = (const float*)&g;
#pragma unroll
        for (int j = 0; j < 4; ++j) {
            const float s2 = ge[j] * ge[j];
            // conservative source-value checks; NaN fails every comparison
            if (!(fe[j] <= 0.0f) || !(fe[j] >= -1.0e37f) ||
                !(s2 >= 1.0e-30f) || !(s2 <= 1.0e30f)) ok = 0;
            local += __builtin_amdgcn_sqrtf((-fe[j]) * __builtin_amdgcn_rcpf(s2));
        }
    }
    // wave-level reduce (64 lanes)
#pragma unroll
    for (int off = 32; off > 0; off >>= 1)
        local += __shfl_xor(local, off, 64);
    ok = __all(ok);
    if ((tid & 63) == 0) { wsum[wave] = local; wok[wave] = ok; }
    __syncthreads();                     // the only barrier
    float total = 0.0f; int allok = 1;
#pragma unroll
    for (int w = 0; w < BLOCK / 64; ++w) { total += wsum[w]; allok &= wok[w]; }

    // ---- samples: 4 per thread, float4 I/O ----
    const int base = (blockIdx.x * BLOCK + tid) * VPT;
    if (base >= B) return;
    float4 xv = make_float4(0.0f, 0.0f, 0.0f, 0.0f);
    const bool full4 = (base + VPT <= B);
    if (full4) {
        xv = *(const float4*)(x + base);
    } else {
        float* xs = (float*)&xv;
        for (int j = 0; j < VPT && base + j < B; ++j) xs[j] = x[base + j];
    }

    const bool fast = allok && (total >= S0_CUTOFF) &&
        (xv.x >= 0.0f) && (xv.y >= 0.0f) &&
        (xv.z >= 0.0f) && (xv.w >= 0.0f);    // NaN x -> false -> slow lane
    if (fast) {
        if (full4) {
            *(float4*)(out + base) = make_float4(0.0f, 0.0f, 0.0f, 0.0f);
        } else {
            for (int j = 0; j < VPT && base + j < B; ++j) out[base + j] = 0.0f;
        }
        return;
    }

    // ---- per-lane slow fallback: exact reference arithmetic ----
    // (exec-masked off entirely when no lane needs it; params from global)
    const float* xs = (const float*)&xv;
    float r[VPT];
#pragma unroll
    for (int j = 0; j < VPT; ++j) {
        const float v = xs[j];
        float s = 0.0f;
        for (int k = 0; k < NPAR; ++k) {
            const float sg = sigma[k];
            s += __builtin_amdgcn_sqrtf((v - fd[k]) / (sg * sg));
        }
        const float o = __expf(-s);
        r[j] = (o != o) ? v : o;            // NaN -> raw input sample
    }
    if (full4) {
        *(float4*)(out + base) = make_float4(r[0], r[1], r[2], r[3]);
    } else {
        for (int j = 0; j < VPT && base + j < B; ++j) out[base + j] = r[j];
    }
}

extern "C" void kernel_launch(void* const* d_in, const int* in_sizes, int n_in,
                              void* d_out, int out_size, void* d_ws, size_t ws_size,
                              hipStream_t stream) {
    const float* x     = (const float*)d_in[0];
    const float* fd    = (const float*)d_in[1];
    const float* sigma = (const float*)d_in[2];
    float* out  = (float*)d_out;
    const int B = in_sizes[0];

    const int grid = (B + BLOCK * VPT - 1) / (BLOCK * VPT);
    fuzzy_fused<<<grid, BLOCK, 0, stream>>>(x, fd, sigma, out, B);
}